// Round 1
// baseline (538.535 us; speedup 1.0000x reference)
//
#include <hip/hip_runtime.h>
#include <hip/hip_bf16.h>

// B=2, S=4096, H=768, NH=12, HD=64
typedef float f32x4 __attribute__((ext_vector_type(4)));
typedef short short8 __attribute__((ext_vector_type(8)));

__device__ __forceinline__ ushort f2bf(float f){
  unsigned u = __builtin_bit_cast(unsigned, f);
  u = (u + 0x7fffu + ((u >> 16) & 1u)) >> 16;
  return (ushort)u;
}

__global__ void cvt_kernel(const float* __restrict__ src, ushort* __restrict__ dst, int n4){
  int i = blockIdx.x * 256 + threadIdx.x;
  if (i < n4){
    float4 v = ((const float4*)src)[i];
    ushort4 o; o.x = f2bf(v.x); o.y = f2bf(v.y); o.z = f2bf(v.z); o.w = f2bf(v.w);
    ((ushort4*)dst)[i] = o;
  }
}

// Out[m,n] = sum_k X[m,k]*W[n,k] + bias[n]   (nn.Linear, B^T-form GEMM)
// X: [8192,768] bf16, W: [768,768] bf16, Out bf16
__global__ __launch_bounds__(256) void qkv_gemm(const ushort* __restrict__ Xb,
                                                const ushort* __restrict__ Wb,
                                                const float* __restrict__ bias,
                                                ushort* __restrict__ Out){
  __shared__ ushort Xs[128*64];   // [row][k] bf16, rows 128B, XOR-swizzled
  __shared__ ushort Ws[128*64];
  const int m0 = blockIdx.x * 128, n0 = blockIdx.y * 128;
  const int tid = threadIdx.x, w = tid >> 6, lane = tid & 63;
  const int r = lane & 15, g = lane >> 4;
  const int wr = (w >> 1) * 64, wc = (w & 1) * 64;
  f32x4 acc[4][4] = {};
  for (int k0 = 0; k0 < 768; k0 += 64){
    #pragma unroll
    for (int p = 0; p < 4; p++){
      int c = tid + 256*p; int row = c >> 3, cir = c & 7;
      uint4 vx = *(const uint4*)(Xb + (size_t)(m0+row)*768 + k0 + cir*8);
      *(uint4*)((char*)Xs + row*128 + ((cir*16) ^ ((row&7)<<4))) = vx;
      uint4 vw = *(const uint4*)(Wb + (size_t)(n0+row)*768 + k0 + cir*8);
      *(uint4*)((char*)Ws + row*128 + ((cir*16) ^ ((row&7)<<4))) = vw;
    }
    __syncthreads();
    #pragma unroll
    for (int ks = 0; ks < 2; ks++){
      short8 af[4], bf[4];
      int bo = ks*64 + g*16;
      #pragma unroll
      for (int i = 0; i < 4; i++){
        int rowa = wr + i*16 + r;
        af[i] = *(const short8*)((char*)Xs + rowa*128 + (bo ^ ((rowa&7)<<4)));
        int rowb = wc + i*16 + r;
        bf[i] = *(const short8*)((char*)Ws + rowb*128 + (bo ^ ((rowb&7)<<4)));
      }
      #pragma unroll
      for (int i = 0; i < 4; i++)
        #pragma unroll
        for (int j = 0; j < 4; j++)
          acc[i][j] = __builtin_amdgcn_mfma_f32_16x16x32_bf16(af[i], bf[j], acc[i][j], 0,0,0);
    }
    __syncthreads();
  }
  #pragma unroll
  for (int i = 0; i < 4; i++){
    #pragma unroll
    for (int j = 0; j < 4; j++){
      int col = n0 + wc + j*16 + r;
      float bv = bias[col];
      int rowb = m0 + wr + i*16 + g*4;
      #pragma unroll
      for (int q = 0; q < 4; q++)
        Out[(size_t)(rowb+q)*768 + col] = f2bf(acc[i][j][q] + bv);
    }
  }
}

// Flash attention: block = (q-tile of 64 rows) x (b,h); 4 waves, wave owns 16 q-rows.
__global__ __launch_bounds__(256) void flash_attn(const ushort* __restrict__ Qb,
                                                  const ushort* __restrict__ Kb,
                                                  const ushort* __restrict__ Vb,
                                                  const float* __restrict__ mask,
                                                  float* __restrict__ out){
  __shared__ ushort Ks[64*64];    // [kv][d], swizzled
  __shared__ ushort Vts[64*64];   // [d][kv], swizzled
  __shared__ ushort Ps[4][16*64]; // per-wave [qrow][kv], swizzled
  const int tid = threadIdx.x, w = tid >> 6, lane = tid & 63;
  const int r = lane & 15, g = lane >> 4;
  const int qt = blockIdx.x, h = blockIdx.y, b = blockIdx.z;
  const int q0 = qt * 64;
  short8 aq0, aq1;
  {
    const ushort* qp = Qb + (size_t)(b*4096 + q0 + w*16 + r)*768 + h*64 + g*8;
    aq0 = *(const short8*)qp;        // d = 8g+j
    aq1 = *(const short8*)(qp + 32); // d = 32+8g+j
  }
  f32x4 ctx[4] = {};
  float mrun[4], lrun[4];
  #pragma unroll
  for (int q = 0; q < 4; q++){ mrun[q] = -1e30f; lrun[q] = 0.f; }

  for (int t = 0; t < 64; t++){
    const int kv0 = t * 64;
    // stage K tile [64][64]
    #pragma unroll
    for (int p = 0; p < 2; p++){
      int c = tid + 256*p; int row = c >> 3, cir = c & 7;
      uint4 vk = *(const uint4*)(Kb + (size_t)(b*4096+kv0+row)*768 + h*64 + cir*8);
      *(uint4*)((char*)Ks + row*128 + ((cir*16) ^ ((row&7)<<4))) = vk;
    }
    // stage V transposed: Vts[d][kv]
    #pragma unroll
    for (int p = 0; p < 2; p++){
      int kv = (tid >> 3) + p*32; int d0 = (tid & 7) * 8;
      union { uint4 v; ushort u[8]; } tmp;
      tmp.v = *(const uint4*)(Vb + (size_t)(b*4096+kv0+kv)*768 + h*64 + d0);
      #pragma unroll
      for (int j = 0; j < 8; j++){
        int d = d0 + j;
        *(ushort*)((char*)Vts + d*128 + ((kv*2) ^ ((d&7)<<4))) = tmp.u[j];
      }
    }
    __syncthreads();
    // S = Q K^T : per wave strip [16 x 64]
    f32x4 s[4];
    #pragma unroll
    for (int c = 0; c < 4; c++){
      int row = c*16 + r; int sw = (row&7) << 4;
      const char* base = (const char*)Ks + row*128;
      short8 bk0 = *(const short8*)(base + ((g*16) ^ sw));
      short8 bk1 = *(const short8*)(base + ((64 + g*16) ^ sw));
      f32x4 z = {};
      z = __builtin_amdgcn_mfma_f32_16x16x32_bf16(aq0, bk0, z, 0,0,0);
      z = __builtin_amdgcn_mfma_f32_16x16x32_bf16(aq1, bk1, z, 0,0,0);
      s[c] = z;
    }
    // scale + mask
    float mval[4];
    #pragma unroll
    for (int c = 0; c < 4; c++) mval[c] = mask[b*4096 + kv0 + c*16 + r];
    #pragma unroll
    for (int c = 0; c < 4; c++)
      #pragma unroll
      for (int q = 0; q < 4; q++) s[c][q] = s[c][q]*0.125f + mval[c];
    // row max (16-lane groups hold a row)
    float mt[4];
    #pragma unroll
    for (int q = 0; q < 4; q++) mt[q] = fmaxf(fmaxf(s[0][q],s[1][q]), fmaxf(s[2][q],s[3][q]));
    #pragma unroll
    for (int off = 1; off < 16; off <<= 1)
      #pragma unroll
      for (int q = 0; q < 4; q++) mt[q] = fmaxf(mt[q], __shfl_xor(mt[q], off, 64));
    float alpha[4];
    #pragma unroll
    for (int q = 0; q < 4; q++){
      float mn = fmaxf(mrun[q], mt[q]);
      alpha[q] = __expf(mrun[q] - mn);
      mrun[q] = mn;
    }
    float rs[4];
    #pragma unroll
    for (int q = 0; q < 4; q++) rs[q] = 0.f;
    #pragma unroll
    for (int c = 0; c < 4; c++)
      #pragma unroll
      for (int q = 0; q < 4; q++){ float pv = __expf(s[c][q] - mrun[q]); s[c][q] = pv; rs[q] += pv; }
    #pragma unroll
    for (int off = 1; off < 16; off <<= 1)
      #pragma unroll
      for (int q = 0; q < 4; q++) rs[q] += __shfl_xor(rs[q], off, 64);
    #pragma unroll
    for (int q = 0; q < 4; q++) lrun[q] = lrun[q]*alpha[q] + rs[q];
    #pragma unroll
    for (int j = 0; j < 4; j++)
      #pragma unroll
      for (int q = 0; q < 4; q++) ctx[j][q] *= alpha[q];
    // write P (bf16) to per-wave LDS, C-layout -> [row][col]
    #pragma unroll
    for (int c = 0; c < 4; c++)
      #pragma unroll
      for (int q = 0; q < 4; q++){
        int row = g*4 + q, col = c*16 + r;
        *(ushort*)((char*)Ps[w] + row*128 + ((col*2) ^ ((row&7)<<4))) = f2bf(s[c][q]);
      }
    // PV: ctx[16 x 64] += P[16 x 64] * V[64 x 64]
    short8 ap0, ap1;
    {
      const char* base = (const char*)Ps[w] + r*128; int sw = (r&7) << 4;
      ap0 = *(const short8*)(base + ((g*16) ^ sw));
      ap1 = *(const short8*)(base + ((64 + g*16) ^ sw));
    }
    #pragma unroll
    for (int j = 0; j < 4; j++){
      int d = j*16 + r; int sw = (d&7) << 4;
      const char* base = (const char*)Vts + d*128;
      short8 bv0 = *(const short8*)(base + ((g*16) ^ sw));
      short8 bv1 = *(const short8*)(base + ((64 + g*16) ^ sw));
      ctx[j] = __builtin_amdgcn_mfma_f32_16x16x32_bf16(ap0, bv0, ctx[j], 0,0,0);
      ctx[j] = __builtin_amdgcn_mfma_f32_16x16x32_bf16(ap1, bv1, ctx[j], 0,0,0);
    }
    __syncthreads();
  }
  // epilogue: out = ctx / l  (fp32)
  #pragma unroll
  for (int q = 0; q < 4; q++){
    float inv = 1.0f / lrun[q];
    #pragma unroll
    for (int j = 0; j < 4; j++){
      int row = q0 + w*16 + g*4 + q;
      int col = h*64 + j*16 + r;
      out[(size_t)(b*4096 + row)*768 + col] = ctx[j][q] * inv;
    }
  }
}

extern "C" void kernel_launch(void* const* d_in, const int* in_sizes, int n_in,
                              void* d_out, int out_size, void* d_ws, size_t ws_size,
                              hipStream_t stream){
  const float* hidden = (const float*)d_in[0];
  const float* mask   = (const float*)d_in[1];
  const float* Wq     = (const float*)d_in[2];
  const float* bq     = (const float*)d_in[3];
  const float* Wk     = (const float*)d_in[4];
  const float* bk     = (const float*)d_in[5];
  const float* Wv     = (const float*)d_in[6];
  const float* bv     = (const float*)d_in[7];
  char* ws = (char*)d_ws;
  ushort* Xb  = (ushort*)(ws);                 // 8192x768 bf16 = 12,582,912 B
  ushort* Wqb = (ushort*)(ws + 12582912);      // 768x768 bf16 = 1,179,648 B
  ushort* Wkb = (ushort*)(ws + 13762560);
  ushort* Wvb = (ushort*)(ws + 14942208);
  ushort* Qb  = (ushort*)(ws + 16121856);      // 8192x768 bf16
  ushort* Kb  = (ushort*)(ws + 28704768);
  ushort* Vb  = (ushort*)(ws + 41287680);      // end = 53,870,592 B

  cvt_kernel<<<6144, 256, 0, stream>>>(hidden, Xb, 1572864);
  cvt_kernel<<<576, 256, 0, stream>>>(Wq, Wqb, 147456);
  cvt_kernel<<<576, 256, 0, stream>>>(Wk, Wkb, 147456);
  cvt_kernel<<<576, 256, 0, stream>>>(Wv, Wvb, 147456);

  dim3 gg(64, 6);
  qkv_gemm<<<gg, 256, 0, stream>>>(Xb, Wqb, bq, Qb);
  qkv_gemm<<<gg, 256, 0, stream>>>(Xb, Wkb, bk, Kb);
  qkv_gemm<<<gg, 256, 0, stream>>>(Xb, Wvb, bv, Vb);

  dim3 ga(64, 12, 2);
  flash_attn<<<ga, 256, 0, stream>>>(Qb, Kb, Vb, mask, (float*)d_out);
}

// Round 3
// 286.775 us; speedup vs baseline: 1.8779x; 1.8779x over previous
//
#include <hip/hip_runtime.h>
#include <hip/hip_bf16.h>

// B=2, S=4096, H=768, NH=12, HD=64
typedef float f32x4 __attribute__((ext_vector_type(4)));
typedef short short8 __attribute__((ext_vector_type(8)));

__device__ __forceinline__ ushort f2bf(float f){
  unsigned u = __builtin_bit_cast(unsigned, f);
  u = (u + 0x7fffu + ((u >> 16) & 1u)) >> 16;
  return (ushort)u;
}

__global__ void cvt_kernel(const float* __restrict__ src, ushort* __restrict__ dst, int n4){
  int i = blockIdx.x * 256 + threadIdx.x;
  if (i < n4){
    float4 v = ((const float4*)src)[i];
    ushort4 o; o.x = f2bf(v.x); o.y = f2bf(v.y); o.z = f2bf(v.z); o.w = f2bf(v.w);
    ((ushort4*)dst)[i] = o;
  }
}

// Out[m,n] = (sum_k X[m,k]*W[n,k] + bias[n]) * scale
__global__ __launch_bounds__(256) void qkv_gemm(const ushort* __restrict__ Xb,
                                                const ushort* __restrict__ Wb,
                                                const float* __restrict__ bias,
                                                ushort* __restrict__ Out,
                                                float scale){
  __shared__ ushort Xs[128*64];
  __shared__ ushort Ws[128*64];
  const int m0 = blockIdx.x * 128, n0 = blockIdx.y * 128;
  const int tid = threadIdx.x, w = tid >> 6, lane = tid & 63;
  const int r = lane & 15, g = lane >> 4;
  const int wr = (w >> 1) * 64, wc = (w & 1) * 64;
  f32x4 acc[4][4] = {};
  for (int k0 = 0; k0 < 768; k0 += 64){
    #pragma unroll
    for (int p = 0; p < 4; p++){
      int c = tid + 256*p; int row = c >> 3, cir = c & 7;
      uint4 vx = *(const uint4*)(Xb + (size_t)(m0+row)*768 + k0 + cir*8);
      *(uint4*)((char*)Xs + row*128 + ((cir*16) ^ ((row&7)<<4))) = vx;
      uint4 vw = *(const uint4*)(Wb + (size_t)(n0+row)*768 + k0 + cir*8);
      *(uint4*)((char*)Ws + row*128 + ((cir*16) ^ ((row&7)<<4))) = vw;
    }
    __syncthreads();
    #pragma unroll
    for (int ks = 0; ks < 2; ks++){
      short8 af[4], bf[4];
      int bo = ks*64 + g*16;
      #pragma unroll
      for (int i = 0; i < 4; i++){
        int rowa = wr + i*16 + r;
        af[i] = *(const short8*)((char*)Xs + rowa*128 + (bo ^ ((rowa&7)<<4)));
        int rowb = wc + i*16 + r;
        bf[i] = *(const short8*)((char*)Ws + rowb*128 + (bo ^ ((rowb&7)<<4)));
      }
      #pragma unroll
      for (int i = 0; i < 4; i++)
        #pragma unroll
        for (int j = 0; j < 4; j++)
          acc[i][j] = __builtin_amdgcn_mfma_f32_16x16x32_bf16(af[i], bf[j], acc[i][j], 0,0,0);
    }
    __syncthreads();
  }
  #pragma unroll
  for (int i = 0; i < 4; i++){
    #pragma unroll
    for (int j = 0; j < 4; j++){
      int col = n0 + wc + j*16 + r;
      float bv = bias[col];
      int rowb = m0 + wr + i*16 + g*4;
      #pragma unroll
      for (int q = 0; q < 4; q++)
        Out[(size_t)(rowb+q)*768 + col] = f2bf((acc[i][j][q] + bv) * scale);
    }
  }
}

// Same GEMM but writes output TRANSPOSED: Vt[(token>>12)*768 + col][token&4095]
__global__ __launch_bounds__(256) void qkv_gemm_vt(const ushort* __restrict__ Xb,
                                                   const ushort* __restrict__ Wb,
                                                   const float* __restrict__ bias,
                                                   ushort* __restrict__ VtOut){
  __shared__ ushort Xs[128*64];
  __shared__ ushort Ws[128*64];
  const int m0 = blockIdx.x * 128, n0 = blockIdx.y * 128;
  const int tid = threadIdx.x, w = tid >> 6, lane = tid & 63;
  const int r = lane & 15, g = lane >> 4;
  const int wr = (w >> 1) * 64, wc = (w & 1) * 64;
  f32x4 acc[4][4] = {};
  for (int k0 = 0; k0 < 768; k0 += 64){
    #pragma unroll
    for (int p = 0; p < 4; p++){
      int c = tid + 256*p; int row = c >> 3, cir = c & 7;
      uint4 vx = *(const uint4*)(Xb + (size_t)(m0+row)*768 + k0 + cir*8);
      *(uint4*)((char*)Xs + row*128 + ((cir*16) ^ ((row&7)<<4))) = vx;
      uint4 vw = *(const uint4*)(Wb + (size_t)(n0+row)*768 + k0 + cir*8);
      *(uint4*)((char*)Ws + row*128 + ((cir*16) ^ ((row&7)<<4))) = vw;
    }
    __syncthreads();
    #pragma unroll
    for (int ks = 0; ks < 2; ks++){
      short8 af[4], bf[4];
      int bo = ks*64 + g*16;
      #pragma unroll
      for (int i = 0; i < 4; i++){
        int rowa = wr + i*16 + r;
        af[i] = *(const short8*)((char*)Xs + rowa*128 + (bo ^ ((rowa&7)<<4)));
        int rowb = wc + i*16 + r;
        bf[i] = *(const short8*)((char*)Ws + rowb*128 + (bo ^ ((rowb&7)<<4)));
      }
      #pragma unroll
      for (int i = 0; i < 4; i++)
        #pragma unroll
        for (int j = 0; j < 4; j++)
          acc[i][j] = __builtin_amdgcn_mfma_f32_16x16x32_bf16(af[i], bf[j], acc[i][j], 0,0,0);
    }
    __syncthreads();
  }
  #pragma unroll
  for (int i = 0; i < 4; i++){
    #pragma unroll
    for (int j = 0; j < 4; j++){
      int col = n0 + wc + j*16 + r;
      float bv = bias[col];
      int rowb = m0 + wr + i*16 + g*4;  // 4 consecutive tokens
      ushort4 o;
      o.x = f2bf(acc[i][j][0] + bv);
      o.y = f2bf(acc[i][j][1] + bv);
      o.z = f2bf(acc[i][j][2] + bv);
      o.w = f2bf(acc[i][j][3] + bv);
      size_t vrow = (size_t)((rowb >> 12) * 768 + col);
      *(ushort4*)(VtOut + vrow * 4096 + (rowb & 4095)) = o;
    }
  }
}

// Flash attention, S^T orientation. Block = 64 q-rows x (b,h); 4 waves x 16 q.
// Q pre-scaled by 0.125. V pre-transposed in global. P goes through a small
// per-wave LDS buffer using only R1-verified primitives (f2bf pack + swizzled
// dword writes + b128 B-frag reads) -- replaces the R2 cvt_pk+shfl path.
__global__ __launch_bounds__(256, 4) void flash_attn(const ushort* __restrict__ Qb,
                                                     const ushort* __restrict__ Kb,
                                                     const ushort* __restrict__ Vt,
                                                     const float* __restrict__ mask,
                                                     float* __restrict__ out){
  __shared__ ushort Ks[64*64];    // [kv][d] swizzled
  __shared__ ushort Vts[64*64];   // [d][kv] swizzled
  __shared__ ushort Ps[4][1024];  // per-wave [q=16][kv=64] swizzled
  const int tid = threadIdx.x, w = tid >> 6, lane = tid & 63;
  const int r = lane & 15, g = lane >> 4;
  const int swr = (r & 7) << 4;
  const int qt = blockIdx.x, h = blockIdx.y, b = blockIdx.z;
  const int q0 = qt * 64;
  char* Pw = (char*)(Ps[w]);

  // Q as B-frag: lane(r,g) holds Q[q = q0+w*16+r][d = g*8+j] (and +32)
  short8 bq0, bq1;
  {
    const ushort* qp = Qb + (size_t)(b*4096 + q0 + w*16 + r)*768 + h*64 + g*8;
    bq0 = *(const short8*)qp;
    bq1 = *(const short8*)(qp + 32);
  }
  const ushort* Kbase = Kb + (size_t)(b*4096)*768 + h*64;
  const ushort* Vbase = Vt + (size_t)(b*768 + h*64)*4096;

  const int row0 = tid >> 3, cir = tid & 7;
  const int row1 = row0 + 32;

  uint4 kreg0, kreg1, vreg0, vreg1;
  kreg0 = *(const uint4*)(Kbase + (size_t)row0*768 + cir*8);
  kreg1 = *(const uint4*)(Kbase + (size_t)row1*768 + cir*8);
  vreg0 = *(const uint4*)(Vbase + (size_t)row0*4096 + cir*8);
  vreg1 = *(const uint4*)(Vbase + (size_t)row1*4096 + cir*8);

  f32x4 ctx[4] = {};
  float mrun = -1e30f, lrun = 0.f;

  for (int t = 0; t < 64; t++){
    const int kv0 = t * 64;
    *(uint4*)((char*)Ks  + row0*128 + ((cir*16) ^ ((row0&7)<<4))) = kreg0;
    *(uint4*)((char*)Ks  + row1*128 + ((cir*16) ^ ((row1&7)<<4))) = kreg1;
    *(uint4*)((char*)Vts + row0*128 + ((cir*16) ^ ((row0&7)<<4))) = vreg0;
    *(uint4*)((char*)Vts + row1*128 + ((cir*16) ^ ((row1&7)<<4))) = vreg1;
    __syncthreads();
    if (t < 63){
      const int kn = kv0 + 64;
      kreg0 = *(const uint4*)(Kbase + (size_t)(kn+row0)*768 + cir*8);
      kreg1 = *(const uint4*)(Kbase + (size_t)(kn+row1)*768 + cir*8);
      vreg0 = *(const uint4*)(Vbase + (size_t)row0*4096 + kn + cir*8);
      vreg1 = *(const uint4*)(Vbase + (size_t)row1*4096 + kn + cir*8);
    }
    // S^T = K Q^T : lane(r,g) gets s[c][e] = S^T[kv = c*16+g*4+e][q = r]
    f32x4 s[4];
    #pragma unroll
    for (int c = 0; c < 4; c++){
      int row = c*16 + r; int sw = (row&7) << 4;
      const char* base = (const char*)Ks + row*128;
      short8 ak0 = *(const short8*)(base + ((g*16) ^ sw));
      short8 ak1 = *(const short8*)(base + ((64 + g*16) ^ sw));
      f32x4 z = {};
      z = __builtin_amdgcn_mfma_f32_16x16x32_bf16(ak0, bq0, z, 0,0,0);
      z = __builtin_amdgcn_mfma_f32_16x16x32_bf16(ak1, bq1, z, 0,0,0);
      s[c] = z;
    }
    #pragma unroll
    for (int c = 0; c < 4; c++){
      float4 mv = *(const float4*)(mask + b*4096 + kv0 + c*16 + g*4);
      s[c][0] += mv.x; s[c][1] += mv.y; s[c][2] += mv.z; s[c][3] += mv.w;
    }
    // online softmax over the lane's q-column (reduce in-lane + across g)
    float mt = s[0][0];
    #pragma unroll
    for (int c = 0; c < 4; c++)
      #pragma unroll
      for (int e = 0; e < 4; e++) mt = fmaxf(mt, s[c][e]);
    mt = fmaxf(mt, __shfl_xor(mt, 16, 64));
    mt = fmaxf(mt, __shfl_xor(mt, 32, 64));
    float mnew = fmaxf(mrun, mt);
    float alpha = __expf(mrun - mnew);
    mrun = mnew;
    float rs = 0.f;
    #pragma unroll
    for (int c = 0; c < 4; c++)
      #pragma unroll
      for (int e = 0; e < 4; e++){ float pv = __expf(s[c][e] - mnew); s[c][e] = pv; rs += pv; }
    rs += __shfl_xor(rs, 16, 64);
    rs += __shfl_xor(rs, 32, 64);
    lrun = lrun * alpha + rs;
    #pragma unroll
    for (int j = 0; j < 4; j++)
      #pragma unroll
      for (int e = 0; e < 4; e++) ctx[j][e] *= alpha;
    // P -> per-wave LDS: row q=r, prebyte kv*2, swizzled by ^swr
    #pragma unroll
    for (int c = 0; c < 4; c++){
      uint lo = (uint)f2bf(s[c][0]) | ((uint)f2bf(s[c][1]) << 16);
      uint hi = (uint)f2bf(s[c][2]) | ((uint)f2bf(s[c][3]) << 16);
      int pre = c*32 + g*8;
      *(uint*)(Pw + r*128 + ((pre    ) ^ swr)) = lo;
      *(uint*)(Pw + r*128 + ((pre + 4) ^ swr)) = hi;
    }
    // PV B-frag: lane(r,g) holds P[q=r][kv = g*8+j] (and +32)
    short8 bp0 = *(const short8*)(Pw + r*128 + ((g*16) ^ swr));
    short8 bp1 = *(const short8*)(Pw + r*128 + ((64 + g*16) ^ swr));
    // ctx^T[d,q] += V^T[d,kv] * P[q,kv]
    #pragma unroll
    for (int j = 0; j < 4; j++){
      int row = j*16 + r; int sw = (row&7) << 4;
      const char* base = (const char*)Vts + row*128;
      short8 av0 = *(const short8*)(base + ((g*16) ^ sw));
      short8 av1 = *(const short8*)(base + ((64 + g*16) ^ sw));
      ctx[j] = __builtin_amdgcn_mfma_f32_16x16x32_bf16(av0, bp0, ctx[j], 0,0,0);
      ctx[j] = __builtin_amdgcn_mfma_f32_16x16x32_bf16(av1, bp1, ctx[j], 0,0,0);
    }
    __syncthreads();
  }
  // epilogue: lane (q=r, g) holds d = j*16 + g*4 + e -> float4 stores
  float inv = 1.0f / lrun;
  size_t orow = (size_t)(b*4096 + q0 + w*16 + r) * 768 + h*64;
  #pragma unroll
  for (int j = 0; j < 4; j++){
    float4 o;
    o.x = ctx[j][0] * inv; o.y = ctx[j][1] * inv;
    o.z = ctx[j][2] * inv; o.w = ctx[j][3] * inv;
    *(float4*)(out + orow + j*16 + g*4) = o;
  }
}

extern "C" void kernel_launch(void* const* d_in, const int* in_sizes, int n_in,
                              void* d_out, int out_size, void* d_ws, size_t ws_size,
                              hipStream_t stream){
  const float* hidden = (const float*)d_in[0];
  const float* mask   = (const float*)d_in[1];
  const float* Wq     = (const float*)d_in[2];
  const float* bq     = (const float*)d_in[3];
  const float* Wk     = (const float*)d_in[4];
  const float* bk     = (const float*)d_in[5];
  const float* Wv     = (const float*)d_in[6];
  const float* bv     = (const float*)d_in[7];
  char* ws = (char*)d_ws;
  ushort* Xb  = (ushort*)(ws);
  ushort* Wqb = (ushort*)(ws + 12582912);
  ushort* Wkb = (ushort*)(ws + 13762560);
  ushort* Wvb = (ushort*)(ws + 14942208);
  ushort* Qb  = (ushort*)(ws + 16121856);
  ushort* Kb  = (ushort*)(ws + 28704768);
  ushort* Vtb = (ushort*)(ws + 41287680);  // [1536][4096] bf16 transposed V

  cvt_kernel<<<6144, 256, 0, stream>>>(hidden, Xb, 1572864);
  cvt_kernel<<<576, 256, 0, stream>>>(Wq, Wqb, 147456);
  cvt_kernel<<<576, 256, 0, stream>>>(Wk, Wkb, 147456);
  cvt_kernel<<<576, 256, 0, stream>>>(Wv, Wvb, 147456);

  dim3 gg(64, 6);
  qkv_gemm<<<gg, 256, 0, stream>>>(Xb, Wqb, bq, Qb, 0.125f);   // fold 1/sqrt(64)
  qkv_gemm<<<gg, 256, 0, stream>>>(Xb, Wkb, bk, Kb, 1.0f);
  qkv_gemm_vt<<<gg, 256, 0, stream>>>(Xb, Wvb, bv, Vtb);

  dim3 ga(64, 12, 2);
  flash_attn<<<ga, 256, 0, stream>>>(Qb, Kb, Vtb, mask, (float*)d_out);
}

// Round 4
// 250.558 us; speedup vs baseline: 2.1493x; 1.1445x over previous
//
#include <hip/hip_runtime.h>
#include <hip/hip_bf16.h>

// B=2, S=4096, H=768, NH=12, HD=64
typedef float f32x4 __attribute__((ext_vector_type(4)));
typedef short short8 __attribute__((ext_vector_type(8)));

__device__ __forceinline__ ushort f2bf(float f){
  unsigned u = __builtin_bit_cast(unsigned, f);
  u = (u + 0x7fffu + ((u >> 16) & 1u)) >> 16;
  return (ushort)u;
}

__global__ void cvt_kernel(const float* __restrict__ src, ushort* __restrict__ dst, int n4){
  int i = blockIdx.x * 256 + threadIdx.x;
  if (i < n4){
    float4 v = ((const float4*)src)[i];
    ushort4 o; o.x = f2bf(v.x); o.y = f2bf(v.y); o.z = f2bf(v.z); o.w = f2bf(v.w);
    ((ushort4*)dst)[i] = o;
  }
}

// Out[m,n] = (sum_k X[m,k]*W[n,k] + bias[n]) * scale
__global__ __launch_bounds__(256) void qkv_gemm(const ushort* __restrict__ Xb,
                                                const ushort* __restrict__ Wb,
                                                const float* __restrict__ bias,
                                                ushort* __restrict__ Out,
                                                float scale){
  __shared__ ushort Xs[128*64];
  __shared__ ushort Ws[128*64];
  const int m0 = blockIdx.x * 128, n0 = blockIdx.y * 128;
  const int tid = threadIdx.x, w = tid >> 6, lane = tid & 63;
  const int r = lane & 15, g = lane >> 4;
  const int wr = (w >> 1) * 64, wc = (w & 1) * 64;
  f32x4 acc[4][4] = {};
  for (int k0 = 0; k0 < 768; k0 += 64){
    #pragma unroll
    for (int p = 0; p < 4; p++){
      int c = tid + 256*p; int row = c >> 3, cir = c & 7;
      uint4 vx = *(const uint4*)(Xb + (size_t)(m0+row)*768 + k0 + cir*8);
      *(uint4*)((char*)Xs + row*128 + ((cir*16) ^ ((row&7)<<4))) = vx;
      uint4 vw = *(const uint4*)(Wb + (size_t)(n0+row)*768 + k0 + cir*8);
      *(uint4*)((char*)Ws + row*128 + ((cir*16) ^ ((row&7)<<4))) = vw;
    }
    __syncthreads();
    #pragma unroll
    for (int ks = 0; ks < 2; ks++){
      short8 af[4], bf[4];
      int bo = ks*64 + g*16;
      #pragma unroll
      for (int i = 0; i < 4; i++){
        int rowa = wr + i*16 + r;
        af[i] = *(const short8*)((char*)Xs + rowa*128 + (bo ^ ((rowa&7)<<4)));
        int rowb = wc + i*16 + r;
        bf[i] = *(const short8*)((char*)Ws + rowb*128 + (bo ^ ((rowb&7)<<4)));
      }
      #pragma unroll
      for (int i = 0; i < 4; i++)
        #pragma unroll
        for (int j = 0; j < 4; j++)
          acc[i][j] = __builtin_amdgcn_mfma_f32_16x16x32_bf16(af[i], bf[j], acc[i][j], 0,0,0);
    }
    __syncthreads();
  }
  #pragma unroll
  for (int i = 0; i < 4; i++){
    #pragma unroll
    for (int j = 0; j < 4; j++){
      int col = n0 + wc + j*16 + r;
      float bv = bias[col];
      int rowb = m0 + wr + i*16 + g*4;
      #pragma unroll
      for (int q = 0; q < 4; q++)
        Out[(size_t)(rowb+q)*768 + col] = f2bf((acc[i][j][q] + bv) * scale);
    }
  }
}

// Same GEMM but writes output TRANSPOSED: Vt[(token>>12)*768 + col][token&4095]
__global__ __launch_bounds__(256) void qkv_gemm_vt(const ushort* __restrict__ Xb,
                                                   const ushort* __restrict__ Wb,
                                                   const float* __restrict__ bias,
                                                   ushort* __restrict__ VtOut){
  __shared__ ushort Xs[128*64];
  __shared__ ushort Ws[128*64];
  const int m0 = blockIdx.x * 128, n0 = blockIdx.y * 128;
  const int tid = threadIdx.x, w = tid >> 6, lane = tid & 63;
  const int r = lane & 15, g = lane >> 4;
  const int wr = (w >> 1) * 64, wc = (w & 1) * 64;
  f32x4 acc[4][4] = {};
  for (int k0 = 0; k0 < 768; k0 += 64){
    #pragma unroll
    for (int p = 0; p < 4; p++){
      int c = tid + 256*p; int row = c >> 3, cir = c & 7;
      uint4 vx = *(const uint4*)(Xb + (size_t)(m0+row)*768 + k0 + cir*8);
      *(uint4*)((char*)Xs + row*128 + ((cir*16) ^ ((row&7)<<4))) = vx;
      uint4 vw = *(const uint4*)(Wb + (size_t)(n0+row)*768 + k0 + cir*8);
      *(uint4*)((char*)Ws + row*128 + ((cir*16) ^ ((row&7)<<4))) = vw;
    }
    __syncthreads();
    #pragma unroll
    for (int ks = 0; ks < 2; ks++){
      short8 af[4], bf[4];
      int bo = ks*64 + g*16;
      #pragma unroll
      for (int i = 0; i < 4; i++){
        int rowa = wr + i*16 + r;
        af[i] = *(const short8*)((char*)Xs + rowa*128 + (bo ^ ((rowa&7)<<4)));
        int rowb = wc + i*16 + r;
        bf[i] = *(const short8*)((char*)Ws + rowb*128 + (bo ^ ((rowb&7)<<4)));
      }
      #pragma unroll
      for (int i = 0; i < 4; i++)
        #pragma unroll
        for (int j = 0; j < 4; j++)
          acc[i][j] = __builtin_amdgcn_mfma_f32_16x16x32_bf16(af[i], bf[j], acc[i][j], 0,0,0);
    }
    __syncthreads();
  }
  #pragma unroll
  for (int i = 0; i < 4; i++){
    #pragma unroll
    for (int j = 0; j < 4; j++){
      int col = n0 + wc + j*16 + r;
      float bv = bias[col];
      int rowb = m0 + wr + i*16 + g*4;  // 4 consecutive tokens
      ushort4 o;
      o.x = f2bf(acc[i][j][0] + bv);
      o.y = f2bf(acc[i][j][1] + bv);
      o.z = f2bf(acc[i][j][2] + bv);
      o.w = f2bf(acc[i][j][3] + bv);
      size_t vrow = (size_t)((rowb >> 12) * 768 + col);
      *(ushort4*)(VtOut + vrow * 4096 + (rowb & 4095)) = o;
    }
  }
}

// Flash attention, S^T orientation. Block = 128 q-rows x (b,h); 4 waves x 32 q
// (two 16-q groups per wave sharing every K/V LDS fragment read).
// Q pre-scaled by 0.125. V pre-transposed in global. Defer-max (THR=8).
__global__ __launch_bounds__(256, 3) void flash_attn(const ushort* __restrict__ Qb,
                                                     const ushort* __restrict__ Kb,
                                                     const ushort* __restrict__ Vt,
                                                     const float* __restrict__ mask,
                                                     float* __restrict__ out){
  __shared__ ushort Ks[64*64];    // [kv][d] swizzled
  __shared__ ushort Vts[64*64];   // [d][kv] swizzled
  __shared__ ushort Ps[4][2048];  // per-wave [q=32][kv=64] swizzled
  const int tid = threadIdx.x, w = tid >> 6, lane = tid & 63;
  const int r = lane & 15, g = lane >> 4;
  const int swr = (r & 7) << 4;
  const int h = blockIdx.y, b = blockIdx.z;
  const int q0 = blockIdx.x * 128 + w * 32;
  char* Pw = (char*)(Ps[w]);

  // Q as B-frags for both groups: lane(r,g) holds Q[q0+grp*16+r][d = g*8+j] (+32)
  short8 bq[2][2];
  #pragma unroll
  for (int grp = 0; grp < 2; grp++){
    const ushort* qp = Qb + (size_t)(b*4096 + q0 + grp*16 + r)*768 + h*64 + g*8;
    bq[grp][0] = *(const short8*)qp;
    bq[grp][1] = *(const short8*)(qp + 32);
  }
  const ushort* Kbase = Kb + (size_t)(b*4096)*768 + h*64;
  const ushort* Vbase = Vt + (size_t)(b*768 + h*64)*4096;

  const int row0 = tid >> 3, cir = tid & 7;
  const int row1 = row0 + 32;

  uint4 kreg0, kreg1, vreg0, vreg1;
  kreg0 = *(const uint4*)(Kbase + (size_t)row0*768 + cir*8);
  kreg1 = *(const uint4*)(Kbase + (size_t)row1*768 + cir*8);
  vreg0 = *(const uint4*)(Vbase + (size_t)row0*4096 + cir*8);
  vreg1 = *(const uint4*)(Vbase + (size_t)row1*4096 + cir*8);

  f32x4 ctx[2][4] = {};
  float mrun[2] = {-1e30f, -1e30f}, lrun[2] = {0.f, 0.f};

  for (int t = 0; t < 64; t++){
    const int kv0 = t * 64;
    *(uint4*)((char*)Ks  + row0*128 + ((cir*16) ^ ((row0&7)<<4))) = kreg0;
    *(uint4*)((char*)Ks  + row1*128 + ((cir*16) ^ ((row1&7)<<4))) = kreg1;
    *(uint4*)((char*)Vts + row0*128 + ((cir*16) ^ ((row0&7)<<4))) = vreg0;
    *(uint4*)((char*)Vts + row1*128 + ((cir*16) ^ ((row1&7)<<4))) = vreg1;
    __syncthreads();
    if (t < 63){
      const int kn = kv0 + 64;
      kreg0 = *(const uint4*)(Kbase + (size_t)(kn+row0)*768 + cir*8);
      kreg1 = *(const uint4*)(Kbase + (size_t)(kn+row1)*768 + cir*8);
      vreg0 = *(const uint4*)(Vbase + (size_t)row0*4096 + kn + cir*8);
      vreg1 = *(const uint4*)(Vbase + (size_t)row1*4096 + kn + cir*8);
    }
    // S^T = K Q^T : lane(r,g) gets s[grp][c][e] = S^T[kv = c*16+g*4+e][q = grp*16+r]
    f32x4 s[2][4];
    #pragma unroll
    for (int c = 0; c < 4; c++){
      int row = c*16 + r; int sw = (row&7) << 4;
      const char* base = (const char*)Ks + row*128;
      short8 ak0 = *(const short8*)(base + ((g*16) ^ sw));
      short8 ak1 = *(const short8*)(base + ((64 + g*16) ^ sw));
      #pragma unroll
      for (int grp = 0; grp < 2; grp++){
        f32x4 z = {};
        z = __builtin_amdgcn_mfma_f32_16x16x32_bf16(ak0, bq[grp][0], z, 0,0,0);
        z = __builtin_amdgcn_mfma_f32_16x16x32_bf16(ak1, bq[grp][1], z, 0,0,0);
        s[grp][c] = z;
      }
    }
    // + mask (per-kv, shared by both groups)
    #pragma unroll
    for (int c = 0; c < 4; c++){
      float4 mv = *(const float4*)(mask + b*4096 + kv0 + c*16 + g*4);
      #pragma unroll
      for (int grp = 0; grp < 2; grp++){
        s[grp][c][0] += mv.x; s[grp][c][1] += mv.y;
        s[grp][c][2] += mv.z; s[grp][c][3] += mv.w;
      }
    }
    #pragma unroll
    for (int grp = 0; grp < 2; grp++){
      // online softmax over the lane's q-column
      float mt = s[grp][0][0];
      #pragma unroll
      for (int c = 0; c < 4; c++)
        #pragma unroll
        for (int e = 0; e < 4; e++) mt = fmaxf(mt, s[grp][c][e]);
      mt = fmaxf(mt, __shfl_xor(mt, 16, 64));
      mt = fmaxf(mt, __shfl_xor(mt, 32, 64));
      // defer-max: only rescale when the tile max grew by more than 8
      if (!__all(mt <= mrun[grp] + 8.0f)){
        float mnew = fmaxf(mrun[grp], mt);
        float alpha = __expf(mrun[grp] - mnew);
        mrun[grp] = mnew;
        lrun[grp] *= alpha;
        #pragma unroll
        for (int j = 0; j < 4; j++)
          #pragma unroll
          for (int e = 0; e < 4; e++) ctx[grp][j][e] *= alpha;
      }
      float rs = 0.f;
      #pragma unroll
      for (int c = 0; c < 4; c++)
        #pragma unroll
        for (int e = 0; e < 4; e++){
          float pv = __expf(s[grp][c][e] - mrun[grp]); s[grp][c][e] = pv; rs += pv;
        }
      rs += __shfl_xor(rs, 16, 64);
      rs += __shfl_xor(rs, 32, 64);
      lrun[grp] += rs;
      // P -> per-wave LDS: row q = grp*16+r, byte kv*2, swizzled (row&7 == r&7)
      char* Pr = Pw + (grp*16 + r)*128;
      #pragma unroll
      for (int c = 0; c < 4; c++){
        uint2 du;
        du.x = (uint)f2bf(s[grp][c][0]) | ((uint)f2bf(s[grp][c][1]) << 16);
        du.y = (uint)f2bf(s[grp][c][2]) | ((uint)f2bf(s[grp][c][3]) << 16);
        *(uint2*)(Pr + ((c*32 + g*8) ^ swr)) = du;
      }
    }
    // PV B-frags: lane(r,g) holds P[q=grp*16+r][kv = g*8+j] (and +32)
    short8 bp[2][2];
    #pragma unroll
    for (int grp = 0; grp < 2; grp++){
      const char* Pr = Pw + (grp*16 + r)*128;
      bp[grp][0] = *(const short8*)(Pr + ((g*16) ^ swr));
      bp[grp][1] = *(const short8*)(Pr + ((64 + g*16) ^ swr));
    }
    // ctx^T[d,q] += V^T[d,kv] * P[q,kv]  (V frags shared by both groups)
    #pragma unroll
    for (int j = 0; j < 4; j++){
      int row = j*16 + r; int sw = (row&7) << 4;
      const char* base = (const char*)Vts + row*128;
      short8 av0 = *(const short8*)(base + ((g*16) ^ sw));
      short8 av1 = *(const short8*)(base + ((64 + g*16) ^ sw));
      #pragma unroll
      for (int grp = 0; grp < 2; grp++){
        ctx[grp][j] = __builtin_amdgcn_mfma_f32_16x16x32_bf16(av0, bp[grp][0], ctx[grp][j], 0,0,0);
        ctx[grp][j] = __builtin_amdgcn_mfma_f32_16x16x32_bf16(av1, bp[grp][1], ctx[grp][j], 0,0,0);
      }
    }
    __syncthreads();
  }
  // epilogue: lane (q=grp*16+r, g) holds d = j*16 + g*4 + e -> float4 stores
  #pragma unroll
  for (int grp = 0; grp < 2; grp++){
    float inv = 1.0f / lrun[grp];
    size_t orow = (size_t)(b*4096 + q0 + grp*16 + r) * 768 + h*64;
    #pragma unroll
    for (int j = 0; j < 4; j++){
      float4 o;
      o.x = ctx[grp][j][0] * inv; o.y = ctx[grp][j][1] * inv;
      o.z = ctx[grp][j][2] * inv; o.w = ctx[grp][j][3] * inv;
      *(float4*)(out + orow + j*16 + g*4) = o;
    }
  }
}

extern "C" void kernel_launch(void* const* d_in, const int* in_sizes, int n_in,
                              void* d_out, int out_size, void* d_ws, size_t ws_size,
                              hipStream_t stream){
  const float* hidden = (const float*)d_in[0];
  const float* mask   = (const float*)d_in[1];
  const float* Wq     = (const float*)d_in[2];
  const float* bq     = (const float*)d_in[3];
  const float* Wk     = (const float*)d_in[4];
  const float* bk     = (const float*)d_in[5];
  const float* Wv     = (const float*)d_in[6];
  const float* bv     = (const float*)d_in[7];
  char* ws = (char*)d_ws;
  ushort* Xb  = (ushort*)(ws);
  ushort* Wqb = (ushort*)(ws + 12582912);
  ushort* Wkb = (ushort*)(ws + 13762560);
  ushort* Wvb = (ushort*)(ws + 14942208);
  ushort* Qb  = (ushort*)(ws + 16121856);
  ushort* Kb  = (ushort*)(ws + 28704768);
  ushort* Vtb = (ushort*)(ws + 41287680);  // [1536][4096] bf16 transposed V

  cvt_kernel<<<6144, 256, 0, stream>>>(hidden, Xb, 1572864);
  cvt_kernel<<<576, 256, 0, stream>>>(Wq, Wqb, 147456);
  cvt_kernel<<<576, 256, 0, stream>>>(Wk, Wkb, 147456);
  cvt_kernel<<<576, 256, 0, stream>>>(Wv, Wvb, 147456);

  dim3 gg(64, 6);
  qkv_gemm<<<gg, 256, 0, stream>>>(Xb, Wqb, bq, Qb, 0.125f);   // fold 1/sqrt(64)
  qkv_gemm<<<gg, 256, 0, stream>>>(Xb, Wkb, bk, Kb, 1.0f);
  qkv_gemm_vt<<<gg, 256, 0, stream>>>(Xb, Wvb, bv, Vtb);

  dim3 ga(32, 12, 2);
  flash_attn<<<ga, 256, 0, stream>>>(Qb, Kb, Vtb, mask, (float*)d_out);
}

// Round 5
// 232.911 us; speedup vs baseline: 2.3122x; 1.0758x over previous
//
#include <hip/hip_runtime.h>
#include <hip/hip_bf16.h>

// B=2, S=4096, H=768, NH=12, HD=64
typedef float f32x4 __attribute__((ext_vector_type(4)));
typedef short short8 __attribute__((ext_vector_type(8)));

#define LOG2E 1.44269504088896340736f

__device__ __forceinline__ ushort f2bf(float f){
  unsigned u = __builtin_bit_cast(unsigned, f);
  u = (u + 0x7fffu + ((u >> 16) & 1u)) >> 16;
  return (ushort)u;
}

// hardware exp2 (schedulable, no volatile)
__device__ __forceinline__ float exp2_hw(float x){
  float r; asm("v_exp_f32 %0, %1" : "=v"(r) : "v"(x)); return r;
}

// pack two f32 -> bf16x2 with round-half-up (1 add per value + 1 v_perm)
__device__ __forceinline__ uint pack_bf16_rh(float lo, float hi){
  uint ul = __builtin_bit_cast(uint, lo) + 0x8000u;
  uint uh = __builtin_bit_cast(uint, hi) + 0x8000u;
  return __builtin_amdgcn_perm(uh, ul, 0x07060302u);
}

__device__ __forceinline__ float fmax3(float a, float b, float c){
  return fmaxf(fmaxf(a, b), c);   // clang fuses to v_max3_f32
}

__global__ void cvt_kernel(const float* __restrict__ src, ushort* __restrict__ dst, int n4){
  int i = blockIdx.x * 256 + threadIdx.x;
  if (i < n4){
    float4 v = ((const float4*)src)[i];
    ushort4 o; o.x = f2bf(v.x); o.y = f2bf(v.y); o.z = f2bf(v.z); o.w = f2bf(v.w);
    ((ushort4*)dst)[i] = o;
  }
}

__global__ void scale_kernel(const float* __restrict__ src, float* __restrict__ dst,
                             float sc, int n){
  int i = blockIdx.x * 256 + threadIdx.x;
  if (i < n) dst[i] = src[i] * sc;
}

// Out[m,n] = (sum_k X[m,k]*W[n,k] + bias[n]) * scale
__global__ __launch_bounds__(256) void qkv_gemm(const ushort* __restrict__ Xb,
                                                const ushort* __restrict__ Wb,
                                                const float* __restrict__ bias,
                                                ushort* __restrict__ Out,
                                                float scale){
  __shared__ ushort Xs[128*64];
  __shared__ ushort Ws[128*64];
  const int m0 = blockIdx.x * 128, n0 = blockIdx.y * 128;
  const int tid = threadIdx.x, w = tid >> 6, lane = tid & 63;
  const int r = lane & 15, g = lane >> 4;
  const int wr = (w >> 1) * 64, wc = (w & 1) * 64;
  f32x4 acc[4][4] = {};
  for (int k0 = 0; k0 < 768; k0 += 64){
    #pragma unroll
    for (int p = 0; p < 4; p++){
      int c = tid + 256*p; int row = c >> 3, cir = c & 7;
      uint4 vx = *(const uint4*)(Xb + (size_t)(m0+row)*768 + k0 + cir*8);
      *(uint4*)((char*)Xs + row*128 + ((cir*16) ^ ((row&7)<<4))) = vx;
      uint4 vw = *(const uint4*)(Wb + (size_t)(n0+row)*768 + k0 + cir*8);
      *(uint4*)((char*)Ws + row*128 + ((cir*16) ^ ((row&7)<<4))) = vw;
    }
    __syncthreads();
    #pragma unroll
    for (int ks = 0; ks < 2; ks++){
      short8 af[4], bf[4];
      int bo = ks*64 + g*16;
      #pragma unroll
      for (int i = 0; i < 4; i++){
        int rowa = wr + i*16 + r;
        af[i] = *(const short8*)((char*)Xs + rowa*128 + (bo ^ ((rowa&7)<<4)));
        int rowb = wc + i*16 + r;
        bf[i] = *(const short8*)((char*)Ws + rowb*128 + (bo ^ ((rowb&7)<<4)));
      }
      #pragma unroll
      for (int i = 0; i < 4; i++)
        #pragma unroll
        for (int j = 0; j < 4; j++)
          acc[i][j] = __builtin_amdgcn_mfma_f32_16x16x32_bf16(af[i], bf[j], acc[i][j], 0,0,0);
    }
    __syncthreads();
  }
  #pragma unroll
  for (int i = 0; i < 4; i++){
    #pragma unroll
    for (int j = 0; j < 4; j++){
      int col = n0 + wc + j*16 + r;
      float bv = bias[col];
      int rowb = m0 + wr + i*16 + g*4;
      #pragma unroll
      for (int q = 0; q < 4; q++)
        Out[(size_t)(rowb+q)*768 + col] = f2bf((acc[i][j][q] + bv) * scale);
    }
  }
}

// Same GEMM but writes output TRANSPOSED: Vt[(token>>12)*768 + col][token&4095]
__global__ __launch_bounds__(256) void qkv_gemm_vt(const ushort* __restrict__ Xb,
                                                   const ushort* __restrict__ Wb,
                                                   const float* __restrict__ bias,
                                                   ushort* __restrict__ VtOut){
  __shared__ ushort Xs[128*64];
  __shared__ ushort Ws[128*64];
  const int m0 = blockIdx.x * 128, n0 = blockIdx.y * 128;
  const int tid = threadIdx.x, w = tid >> 6, lane = tid & 63;
  const int r = lane & 15, g = lane >> 4;
  const int wr = (w >> 1) * 64, wc = (w & 1) * 64;
  f32x4 acc[4][4] = {};
  for (int k0 = 0; k0 < 768; k0 += 64){
    #pragma unroll
    for (int p = 0; p < 4; p++){
      int c = tid + 256*p; int row = c >> 3, cir = c & 7;
      uint4 vx = *(const uint4*)(Xb + (size_t)(m0+row)*768 + k0 + cir*8);
      *(uint4*)((char*)Xs + row*128 + ((cir*16) ^ ((row&7)<<4))) = vx;
      uint4 vw = *(const uint4*)(Wb + (size_t)(n0+row)*768 + k0 + cir*8);
      *(uint4*)((char*)Ws + row*128 + ((cir*16) ^ ((row&7)<<4))) = vw;
    }
    __syncthreads();
    #pragma unroll
    for (int ks = 0; ks < 2; ks++){
      short8 af[4], bf[4];
      int bo = ks*64 + g*16;
      #pragma unroll
      for (int i = 0; i < 4; i++){
        int rowa = wr + i*16 + r;
        af[i] = *(const short8*)((char*)Xs + rowa*128 + (bo ^ ((rowa&7)<<4)));
        int rowb = wc + i*16 + r;
        bf[i] = *(const short8*)((char*)Ws + rowb*128 + (bo ^ ((rowb&7)<<4)));
      }
      #pragma unroll
      for (int i = 0; i < 4; i++)
        #pragma unroll
        for (int j = 0; j < 4; j++)
          acc[i][j] = __builtin_amdgcn_mfma_f32_16x16x32_bf16(af[i], bf[j], acc[i][j], 0,0,0);
    }
    __syncthreads();
  }
  #pragma unroll
  for (int i = 0; i < 4; i++){
    #pragma unroll
    for (int j = 0; j < 4; j++){
      int col = n0 + wc + j*16 + r;
      float bv = bias[col];
      int rowb = m0 + wr + i*16 + g*4;  // 4 consecutive tokens
      ushort4 o;
      o.x = f2bf(acc[i][j][0] + bv);
      o.y = f2bf(acc[i][j][1] + bv);
      o.z = f2bf(acc[i][j][2] + bv);
      o.w = f2bf(acc[i][j][3] + bv);
      size_t vrow = (size_t)((rowb >> 12) * 768 + col);
      *(ushort4*)(VtOut + vrow * 4096 + (rowb & 4095)) = o;
    }
  }
}

// Flash attention, S^T orientation, log2-domain softmax.
// Block = 128 q x (b,h); 4 waves x 32 q (two 16-q groups share K/V frag reads).
// Q pre-scaled by 0.125*log2e in Q-GEMM; mask pre-scaled by log2e (maskL).
// V pre-transposed in global. Defer-max THR = 8*log2e.
__global__ __launch_bounds__(256, 3) void flash_attn(const ushort* __restrict__ Qb,
                                                     const ushort* __restrict__ Kb,
                                                     const ushort* __restrict__ Vt,
                                                     const float* __restrict__ maskL,
                                                     float* __restrict__ out){
  __shared__ ushort Ks[64*64];    // [kv][d] swizzled
  __shared__ ushort Vts[64*64];   // [d][kv] swizzled
  __shared__ ushort Ps[4][2048];  // per-wave [q=32][kv=64] swizzled
  const int tid = threadIdx.x, w = tid >> 6, lane = tid & 63;
  const int r = lane & 15, g = lane >> 4;
  const int swr = (r & 7) << 4;
  const int h = blockIdx.y, b = blockIdx.z;
  const int q0 = blockIdx.x * 128 + w * 32;
  char* Pw = (char*)(Ps[w]);

  short8 bq[2][2];
  #pragma unroll
  for (int grp = 0; grp < 2; grp++){
    const ushort* qp = Qb + (size_t)(b*4096 + q0 + grp*16 + r)*768 + h*64 + g*8;
    bq[grp][0] = *(const short8*)qp;
    bq[grp][1] = *(const short8*)(qp + 32);
  }
  const ushort* Kbase = Kb + (size_t)(b*4096)*768 + h*64;
  const ushort* Vbase = Vt + (size_t)(b*768 + h*64)*4096;

  const int row0 = tid >> 3, cir = tid & 7;
  const int row1 = row0 + 32;

  uint4 kreg0, kreg1, vreg0, vreg1;
  kreg0 = *(const uint4*)(Kbase + (size_t)row0*768 + cir*8);
  kreg1 = *(const uint4*)(Kbase + (size_t)row1*768 + cir*8);
  vreg0 = *(const uint4*)(Vbase + (size_t)row0*4096 + cir*8);
  vreg1 = *(const uint4*)(Vbase + (size_t)row1*4096 + cir*8);

  f32x4 ctx[2][4] = {};
  float mrun[2] = {-1e30f, -1e30f}, lrun[2] = {0.f, 0.f};

  for (int t = 0; t < 64; t++){
    const int kv0 = t * 64;
    *(uint4*)((char*)Ks  + row0*128 + ((cir*16) ^ ((row0&7)<<4))) = kreg0;
    *(uint4*)((char*)Ks  + row1*128 + ((cir*16) ^ ((row1&7)<<4))) = kreg1;
    *(uint4*)((char*)Vts + row0*128 + ((cir*16) ^ ((row0&7)<<4))) = vreg0;
    *(uint4*)((char*)Vts + row1*128 + ((cir*16) ^ ((row1&7)<<4))) = vreg1;
    __syncthreads();
    if (t < 63){
      const int kn = kv0 + 64;
      kreg0 = *(const uint4*)(Kbase + (size_t)(kn+row0)*768 + cir*8);
      kreg1 = *(const uint4*)(Kbase + (size_t)(kn+row1)*768 + cir*8);
      vreg0 = *(const uint4*)(Vbase + (size_t)row0*4096 + kn + cir*8);
      vreg1 = *(const uint4*)(Vbase + (size_t)row1*4096 + kn + cir*8);
    }
    // S^T = K Q^T (log2 units): s[grp][c][e] = S^T[kv=c*16+g*4+e][q=grp*16+r]
    f32x4 s[2][4];
    #pragma unroll
    for (int c = 0; c < 4; c++){
      int row = c*16 + r; int sw = (row&7) << 4;
      const char* base = (const char*)Ks + row*128;
      short8 ak0 = *(const short8*)(base + ((g*16) ^ sw));
      short8 ak1 = *(const short8*)(base + ((64 + g*16) ^ sw));
      #pragma unroll
      for (int grp = 0; grp < 2; grp++){
        f32x4 z = {};
        z = __builtin_amdgcn_mfma_f32_16x16x32_bf16(ak0, bq[grp][0], z, 0,0,0);
        z = __builtin_amdgcn_mfma_f32_16x16x32_bf16(ak1, bq[grp][1], z, 0,0,0);
        s[grp][c] = z;
      }
    }
    #pragma unroll
    for (int c = 0; c < 4; c++){
      float4 mv = *(const float4*)(maskL + b*4096 + kv0 + c*16 + g*4);
      #pragma unroll
      for (int grp = 0; grp < 2; grp++){
        s[grp][c][0] += mv.x; s[grp][c][1] += mv.y;
        s[grp][c][2] += mv.z; s[grp][c][3] += mv.w;
      }
    }
    #pragma unroll
    for (int grp = 0; grp < 2; grp++){
      // max via max3 chains (two parallel chains for ILP)
      float ma = fmax3(s[grp][0][0], s[grp][0][1], s[grp][0][2]);
      ma = fmax3(ma, s[grp][0][3], s[grp][1][0]);
      ma = fmax3(ma, s[grp][1][1], s[grp][1][2]);
      float mb = fmax3(s[grp][1][3], s[grp][2][0], s[grp][2][1]);
      mb = fmax3(mb, s[grp][2][2], s[grp][2][3]);
      mb = fmax3(mb, s[grp][3][0], s[grp][3][1]);
      float mt = fmax3(s[grp][3][2], s[grp][3][3], fmaxf(ma, mb));
      mt = fmaxf(mt, __shfl_xor(mt, 16, 64));
      mt = fmaxf(mt, __shfl_xor(mt, 32, 64));
      // defer-max: rescale only when tile max grew > 8*log2e (log2 units)
      if (!__all(mt <= mrun[grp] + 11.5415603f)){
        float mnew = fmaxf(mrun[grp], mt);
        float alpha = exp2_hw(mrun[grp] - mnew);
        mrun[grp] = mnew;
        lrun[grp] *= alpha;
        #pragma unroll
        for (int j = 0; j < 4; j++)
          #pragma unroll
          for (int e = 0; e < 4; e++) ctx[grp][j][e] *= alpha;
      }
      float rs = 0.f;
      #pragma unroll
      for (int c = 0; c < 4; c++)
        #pragma unroll
        for (int e = 0; e < 4; e++){
          float pv = exp2_hw(s[grp][c][e] - mrun[grp]); s[grp][c][e] = pv; rs += pv;
        }
      rs += __shfl_xor(rs, 16, 64);
      rs += __shfl_xor(rs, 32, 64);
      lrun[grp] += rs;
      // P -> per-wave LDS (round-half-up pack, 1 v_perm per pair)
      char* Pr = Pw + (grp*16 + r)*128;
      #pragma unroll
      for (int c = 0; c < 4; c++){
        uint2 du;
        du.x = pack_bf16_rh(s[grp][c][0], s[grp][c][1]);
        du.y = pack_bf16_rh(s[grp][c][2], s[grp][c][3]);
        *(uint2*)(Pr + ((c*32 + g*8) ^ swr)) = du;
      }
    }
    short8 bp[2][2];
    #pragma unroll
    for (int grp = 0; grp < 2; grp++){
      const char* Pr = Pw + (grp*16 + r)*128;
      bp[grp][0] = *(const short8*)(Pr + ((g*16) ^ swr));
      bp[grp][1] = *(const short8*)(Pr + ((64 + g*16) ^ swr));
    }
    #pragma unroll
    for (int j = 0; j < 4; j++){
      int row = j*16 + r; int sw = (row&7) << 4;
      const char* base = (const char*)Vts + row*128;
      short8 av0 = *(const short8*)(base + ((g*16) ^ sw));
      short8 av1 = *(const short8*)(base + ((64 + g*16) ^ sw));
      #pragma unroll
      for (int grp = 0; grp < 2; grp++){
        ctx[grp][j] = __builtin_amdgcn_mfma_f32_16x16x32_bf16(av0, bp[grp][0], ctx[grp][j], 0,0,0);
        ctx[grp][j] = __builtin_amdgcn_mfma_f32_16x16x32_bf16(av1, bp[grp][1], ctx[grp][j], 0,0,0);
      }
    }
    __syncthreads();
  }
  #pragma unroll
  for (int grp = 0; grp < 2; grp++){
    float inv = 1.0f / lrun[grp];
    size_t orow = (size_t)(b*4096 + q0 + grp*16 + r) * 768 + h*64;
    #pragma unroll
    for (int j = 0; j < 4; j++){
      float4 o;
      o.x = ctx[grp][j][0] * inv; o.y = ctx[grp][j][1] * inv;
      o.z = ctx[grp][j][2] * inv; o.w = ctx[grp][j][3] * inv;
      *(float4*)(out + orow + j*16 + g*4) = o;
    }
  }
}

extern "C" void kernel_launch(void* const* d_in, const int* in_sizes, int n_in,
                              void* d_out, int out_size, void* d_ws, size_t ws_size,
                              hipStream_t stream){
  const float* hidden = (const float*)d_in[0];
  const float* mask   = (const float*)d_in[1];
  const float* Wq     = (const float*)d_in[2];
  const float* bq     = (const float*)d_in[3];
  const float* Wk     = (const float*)d_in[4];
  const float* bk     = (const float*)d_in[5];
  const float* Wv     = (const float*)d_in[6];
  const float* bv     = (const float*)d_in[7];
  char* ws = (char*)d_ws;
  ushort* Xb    = (ushort*)(ws);
  ushort* Wqb   = (ushort*)(ws + 12582912);
  ushort* Wkb   = (ushort*)(ws + 13762560);
  ushort* Wvb   = (ushort*)(ws + 14942208);
  ushort* Qb    = (ushort*)(ws + 16121856);
  ushort* Kb    = (ushort*)(ws + 28704768);
  ushort* Vtb   = (ushort*)(ws + 41287680);  // [1536][4096] bf16 transposed V
  float*  maskL = (float*)(ws + 53870592);   // mask * log2e, 8192 f32

  cvt_kernel<<<6144, 256, 0, stream>>>(hidden, Xb, 1572864);
  cvt_kernel<<<576, 256, 0, stream>>>(Wq, Wqb, 147456);
  cvt_kernel<<<576, 256, 0, stream>>>(Wk, Wkb, 147456);
  cvt_kernel<<<576, 256, 0, stream>>>(Wv, Wvb, 147456);
  scale_kernel<<<32, 256, 0, stream>>>(mask, maskL, LOG2E, 8192);

  dim3 gg(64, 6);
  qkv_gemm<<<gg, 256, 0, stream>>>(Xb, Wqb, bq, Qb, 0.125f * LOG2E);
  qkv_gemm<<<gg, 256, 0, stream>>>(Xb, Wkb, bk, Kb, 1.0f);
  qkv_gemm_vt<<<gg, 256, 0, stream>>>(Xb, Wvb, bv, Vtb);

  dim3 ga(32, 12, 2);
  flash_attn<<<ga, 256, 0, stream>>>(Qb, Kb, Vtb, maskL, (float*)d_out);
}